// Round 17
// baseline (177.940 us; speedup 1.0000x reference)
//
#include <hip/hip_runtime.h>

typedef __attribute__((ext_vector_type(2))) float f32x2;

#define W 4096
#define H 4096
#define NT 256
#define COLS 512                 // columns per block (2 per thread)
#define SR 32                    // output rows per block strip
#define GROUP 8                  // rows staged per barrier (2 per wave, DMA)
#define NSTAGE (SR + 14)         // 46 staged rows contribute
#define NG 6                     // 6 groups of 8 (48 slots, last 2 guarded)
#define LW 528                   // staged row: float f <-> col c0-8+f
#define RAD 7
#define PEND 22                  // 15 + GROUP - 1

__device__ __forceinline__ void gl_lds16(float* lds, const float* g) {
    __builtin_amdgcn_global_load_lds(
        (const __attribute__((address_space(1))) void*)g,
        (__attribute__((address_space(3))) void*)lds, 16, 0, 0);
}
__device__ __forceinline__ void gl_lds4(float* lds, const float* g) {
    __builtin_amdgcn_global_load_lds(
        (const __attribute__((address_space(1))) void*)g,
        (__attribute__((address_space(3))) void*)lds, 4, 0, 0);
}

__global__ __launch_bounds__(NT, 4) void multibox_kernel(
    const float* __restrict__ x, const float* __restrict__ base,
    float* __restrict__ out)
{
    __shared__ float buf[2][GROUP][LW];   // 33,792 B -> 4 blocks/CU fits

    const int t  = threadIdx.x;
    const int w  = t >> 6;                // wave id (0..3)
    const int l  = t & 63;                // lane
    const int c0 = blockIdx.x * COLS;
    const int i0 = blockIdx.y * SR;

    const float w3  = 1.f/(7.f*9.f);
    const float w5  = 1.f/(7.f*25.f);
    const float w7  = 1.f/(7.f*49.f);
    const float w9  = 1.f/(7.f*81.f);
    const float w11 = 1.f/(7.f*121.f);
    const float w13 = 1.f/(7.f*169.f);
    const float w15 = 1.f/(7.f*225.f);

    // Exact-edge 4-op DMA per row (float f <-> col c0-8+f, f = 0..527):
    //  L : f 0..63    4B/lane x64, per-lane clamp -> exact edge replicate
    //  M1: f 64..319  16B/lane x64, cols c0+56..c0+311 always in-range
    //  M2: f 320..511 16B/lane, lanes 0..47, cols <= c0+503 in-range
    //  R : f 512..527 4B/lane, lanes 0..15, per-lane clamp -> exact replicate
    const int colL  = min(max(c0 -   8 +     l, 0), W - 1);
    const int colM1 =         c0 +  56 + 4 * l;
    const int colM2 =         c0 + 312 + 4 * l;
    const int colR  = min(    c0 + 504 +     l,     W - 1);

    // wave w stages rows {w, w+4} of group g into slot b: 8 DMA ops/wave
    auto stage = [&](int g, int b) {
#pragma unroll
        for (int k = 0; k < 2; ++k) {
            const int rr = w + 4 * k;
            const int rc = min(max(i0 - RAD + g * GROUP + rr, 0), H - 1);
            const float* rp = x + (size_t)rc * W;
            float* lb = &buf[b][rr][0];
            gl_lds4(lb, rp + colL);
            gl_lds16(lb + 64, rp + colM1);
            if (l < 48) gl_lds16(lb + 320, rp + colM2);
            if (l < 16) gl_lds4 (lb + 512, rp + colR);
        }
    };

    // Pnd[p] accumulates output row (i0 + 8g - 14 + p) before group g.
    // rr / p compile-time (inner unrolls); g stays RUNTIME (rounds 4/7 lesson).
    f32x2 Pnd[PEND];
#pragma unroll
    for (int q = 0; q < PEND; ++q) Pnd[q] = f32x2{0.f, 0.f};

    auto compute_group = [&](int b, int g) {
#pragma unroll
        for (int rr = 0; rr < GROUP; ++rr) {
            if (g * GROUP + rr < NSTAGE) {
                const float* p = &buf[b][rr][2 * t];   // floats 2t .. 2t+17
                f32x2 q2[9];
#pragma unroll
                for (int i = 0; i < 9; ++i) q2[i] = *(const f32x2*)(p + 2 * i);

                auto PR = [&](int a) -> f32x2 {        // cols {j-8+a, j-7+a}
                    if ((a & 1) == 0) return q2[a / 2];
                    f32x2 r;
                    r.x = q2[a / 2].y;
                    r.y = q2[a / 2 + 1].x;
                    return r;
                };

                f32x2 s3  = PR(7) + PR(8) + PR(9);
                f32x2 s5  = s3  + PR(6) + PR(10);
                f32x2 s7  = s5  + PR(5) + PR(11);
                f32x2 s9  = s7  + PR(4) + PR(12);
                f32x2 s11 = s9  + PR(3) + PR(13);
                f32x2 s13 = s11 + PR(2) + PR(14);
                f32x2 s15 = s13 + PR(1) + PR(15);

                f32x2 c7 = f32x2{w15, w15} * s15;
                f32x2 c6 = c7 + f32x2{w13, w13} * s13;
                f32x2 c5 = c6 + f32x2{w11, w11} * s11;
                f32x2 c4 = c5 + f32x2{w9 , w9 } * s9;
                f32x2 c3 = c4 + f32x2{w7 , w7 } * s7;
                f32x2 c2 = c3 + f32x2{w5 , w5 } * s5;
                f32x2 c1 = c2 + f32x2{w3 , w3 } * s3;

                Pnd[rr +  0] += c7; Pnd[rr +  1] += c6; Pnd[rr +  2] += c5;
                Pnd[rr +  3] += c4; Pnd[rr +  4] += c3; Pnd[rr +  5] += c2;
                Pnd[rr +  6] += c1; Pnd[rr +  7] += c1; Pnd[rr +  8] += c1;
                Pnd[rr +  9] += c2; Pnd[rr + 10] += c3; Pnd[rr + 11] += c4;
                Pnd[rr + 12] += c5; Pnd[rr + 13] += c6; Pnd[rr + 14] += c7;
            }
        }

        // emit the completed output rows: o_ofs = 8g - 14 + p, p = 0..7
#pragma unroll
        for (int p = 0; p < GROUP; ++p) {
            const int o_ofs = 8 * g - 14 + p;
            if (o_ofs >= 0 && o_ofs < SR) {
                const size_t bi = (size_t)(i0 + o_ofs) * W + c0 + 2 * t;
                f32x2 bm = *(const f32x2*)(base + bi);
                f32x2 ov = Pnd[p] * bm;
                *(f32x2*)(out + bi) = ov;
            }
        }

        // shift window by GROUP (static indices)
#pragma unroll
        for (int p = 0; p < PEND - GROUP; ++p) Pnd[p] = Pnd[p + GROUP];
#pragma unroll
        for (int p = PEND - GROUP; p < PEND; ++p) Pnd[p] = f32x2{0.f, 0.f};
    };

    stage(0, 0);
    __syncthreads();                       // drains DMA + orders LDS

    // 6 barrier intervals (was 12). MUST stay rolled (round-7 spill lesson).
#pragma clang loop unroll(disable)
    for (int g = 0; g < NG - 1; ++g) {
        stage(g + 1, (g + 1) & 1);   // issue next group's 8 DMA ops early
        compute_group(g & 1, g);     // 72 ds_read_b64 + VALU + 8-row emit
        __syncthreads();             // next group's rows landed
    }
    compute_group((NG - 1) & 1, NG - 1);
}

extern "C" void kernel_launch(void* const* d_in, const int* in_sizes, int n_in,
                              void* d_out, int out_size, void* d_ws, size_t ws_size,
                              hipStream_t stream) {
    const float* x    = (const float*)d_in[0];
    const float* base = (const float*)d_in[1];
    float* out        = (float*)d_out;

    dim3 grid(W / COLS, H / SR);   // (8, 128) = 1024 blocks
    multibox_kernel<<<grid, dim3(NT), 0, stream>>>(x, base, out);
}

// Round 18
// 73.378 us; speedup vs baseline: 2.4250x; 2.4250x over previous
//
#include <hip/hip_runtime.h>

typedef __attribute__((ext_vector_type(2))) float f32x2;

#define W 4096
#define H 4096
#define NT 256
#define COLS 512                 // columns per block (2 per thread)
#define SR 32                    // output rows per block strip
#define GROUP 6                  // rows staged per barrier
#define NSTAGE (SR + 14)         // 46 staged rows contribute
#define NG 8                     // 8 groups of 6 (48 slots, last 2 guarded)
#define LW 528                   // staged row: float f <-> col c0-8+f
#define RAD 7
#define PEND 20                  // 15 + GROUP - 1

__device__ __forceinline__ void gl_lds16(float* lds, const float* g) {
    __builtin_amdgcn_global_load_lds(
        (const __attribute__((address_space(1))) void*)g,
        (__attribute__((address_space(3))) void*)lds, 16, 0, 0);
}
__device__ __forceinline__ void gl_lds4(float* lds, const float* g) {
    __builtin_amdgcn_global_load_lds(
        (const __attribute__((address_space(1))) void*)g,
        (__attribute__((address_space(3))) void*)lds, 4, 0, 0);
}

__global__ __launch_bounds__(NT, 4) void multibox_kernel(
    const float* __restrict__ x, const float* __restrict__ base,
    float* __restrict__ out)
{
    __shared__ float buf[2][GROUP][LW];   // 25,344 B -> 4 blocks/CU fits LDS

    const int t  = threadIdx.x;
    const int w  = t >> 6;                // wave id (0..3)
    const int l  = t & 63;                // lane
    const int c0 = blockIdx.x * COLS;
    const int i0 = blockIdx.y * SR;

    const float w3  = 1.f/(7.f*9.f);
    const float w5  = 1.f/(7.f*25.f);
    const float w7  = 1.f/(7.f*49.f);
    const float w9  = 1.f/(7.f*81.f);
    const float w11 = 1.f/(7.f*121.f);
    const float w13 = 1.f/(7.f*169.f);
    const float w15 = 1.f/(7.f*225.f);

    // Exact-edge 4-op DMA per row (float f <-> col c0-8+f, f = 0..527):
    //  L : f 0..63    4B/lane x64, per-lane clamp -> exact edge replicate
    //  M1: f 64..319  16B/lane x64, cols c0+56..c0+311 always in-range
    //  M2: f 320..511 16B/lane, lanes 0..47, cols <= c0+503 in-range
    //  R : f 512..527 4B/lane, lanes 0..15, per-lane clamp -> exact replicate
    const int colL  = min(max(c0 -   8 +     l, 0), W - 1);
    const int colM1 =         c0 +  56 + 4 * l;
    const int colM2 =         c0 + 312 + 4 * l;
    const int colR  = min(    c0 + 504 +     l,     W - 1);

    // group g, slot b: waves 0-1 stage rows {w, w+4}; waves 2-3 stage row w
    auto stage = [&](int g, int b) {
#pragma unroll
        for (int k = 0; k < 2; ++k) {
            const int rr = w + 4 * k;
            if (rr < GROUP) {
                const int rc = min(max(i0 - RAD + g * GROUP + rr, 0), H - 1);
                const float* rp = x + (size_t)rc * W;
                float* lb = &buf[b][rr][0];
                gl_lds4(lb, rp + colL);
                gl_lds16(lb + 64, rp + colM1);
                if (l < 48) gl_lds16(lb + 320, rp + colM2);
                if (l < 16) gl_lds4 (lb + 512, rp + colR);
            }
        }
    };

    // Pnd[p] accumulates output row (i0 + 6g - 14 + p) before group g.
    // rr / p compile-time (inner unrolls); g stays RUNTIME (rounds 4/7 lesson).
    f32x2 Pnd[PEND];
#pragma unroll
    for (int q = 0; q < PEND; ++q) Pnd[q] = f32x2{0.f, 0.f};

    auto compute_group = [&](int b, int g) {
#pragma unroll
        for (int rr = 0; rr < GROUP; ++rr) {
            if (g * GROUP + rr < NSTAGE) {
                const float* p = &buf[b][rr][2 * t];   // floats 2t .. 2t+17
                f32x2 q2[9];
#pragma unroll
                for (int i = 0; i < 9; ++i) q2[i] = *(const f32x2*)(p + 2 * i);

                auto PR = [&](int a) -> f32x2 {        // cols {j-8+a, j-7+a}
                    if ((a & 1) == 0) return q2[a / 2];
                    f32x2 r;
                    r.x = q2[a / 2].y;
                    r.y = q2[a / 2 + 1].x;
                    return r;
                };

                f32x2 s3  = PR(7) + PR(8) + PR(9);
                f32x2 s5  = s3  + PR(6) + PR(10);
                f32x2 s7  = s5  + PR(5) + PR(11);
                f32x2 s9  = s7  + PR(4) + PR(12);
                f32x2 s11 = s9  + PR(3) + PR(13);
                f32x2 s13 = s11 + PR(2) + PR(14);
                f32x2 s15 = s13 + PR(1) + PR(15);

                f32x2 c7 = f32x2{w15, w15} * s15;
                f32x2 c6 = c7 + f32x2{w13, w13} * s13;
                f32x2 c5 = c6 + f32x2{w11, w11} * s11;
                f32x2 c4 = c5 + f32x2{w9 , w9 } * s9;
                f32x2 c3 = c4 + f32x2{w7 , w7 } * s7;
                f32x2 c2 = c3 + f32x2{w5 , w5 } * s5;
                f32x2 c1 = c2 + f32x2{w3 , w3 } * s3;

                Pnd[rr +  0] += c7; Pnd[rr +  1] += c6; Pnd[rr +  2] += c5;
                Pnd[rr +  3] += c4; Pnd[rr +  4] += c3; Pnd[rr +  5] += c2;
                Pnd[rr +  6] += c1; Pnd[rr +  7] += c1; Pnd[rr +  8] += c1;
                Pnd[rr +  9] += c2; Pnd[rr + 10] += c3; Pnd[rr + 11] += c4;
                Pnd[rr + 12] += c5; Pnd[rr + 13] += c6; Pnd[rr + 14] += c7;
            }
        }

        // emit the completed output rows: o_ofs = 6g - 14 + p, p = 0..5
#pragma unroll
        for (int p = 0; p < GROUP; ++p) {
            const int o_ofs = 6 * g - 14 + p;
            if (o_ofs >= 0 && o_ofs < SR) {
                const size_t bi = (size_t)(i0 + o_ofs) * W + c0 + 2 * t;
                f32x2 bm = *(const f32x2*)(base + bi);
                f32x2 ov = Pnd[p] * bm;
                *(f32x2*)(out + bi) = ov;
            }
        }

        // shift window by GROUP (static indices)
#pragma unroll
        for (int p = 0; p < PEND - GROUP; ++p) Pnd[p] = Pnd[p + GROUP];
#pragma unroll
        for (int p = PEND - GROUP; p < PEND; ++p) Pnd[p] = f32x2{0.f, 0.f};
    };

    stage(0, 0);
    __syncthreads();                       // drains DMA + orders LDS

    // 8 barrier intervals (was 12). MUST stay rolled (round-7 spill lesson).
#pragma clang loop unroll(disable)
    for (int g = 0; g < NG - 1; ++g) {
        stage(g + 1, (g + 1) & 1);   // issue next group's DMA ops early
        compute_group(g & 1, g);     // 54 ds_read_b64 + VALU + 6-row emit
        __syncthreads();             // next group's rows landed
    }
    compute_group((NG - 1) & 1, NG - 1);
}

extern "C" void kernel_launch(void* const* d_in, const int* in_sizes, int n_in,
                              void* d_out, int out_size, void* d_ws, size_t ws_size,
                              hipStream_t stream) {
    const float* x    = (const float*)d_in[0];
    const float* base = (const float*)d_in[1];
    float* out        = (float*)d_out;

    dim3 grid(W / COLS, H / SR);   // (8, 128) = 1024 blocks
    multibox_kernel<<<grid, dim3(NT), 0, stream>>>(x, base, out);
}

// Round 19
// 45.565 us; speedup vs baseline: 3.9052x; 1.6104x over previous
//
#include <hip/hip_runtime.h>

typedef __attribute__((ext_vector_type(2))) float f32x2;

#define W 4096
#define H 4096
#define NT 256
#define NW 4
#define COLS 512                 // columns per block (2 per thread)
#define SR 32                    // output rows per block strip
#define GROUP 4                  // rows staged per barrier (1 per wave, DMA)
#define NSTAGE (SR + 14)         // 46 staged rows contribute
#define NG 12                    // 12 groups of 4
#define LW 576                   // padded staged row: 2*256 + 64 floats (DMA-linear)
#define RAD 7
#define PEND 18                  // 15 + GROUP - 1  (fits the 64-VGPR budget)

__device__ __forceinline__ void gl_lds16(float* lds, const float* g) {
    __builtin_amdgcn_global_load_lds(
        (const __attribute__((address_space(1))) void*)g,
        (__attribute__((address_space(3))) void*)lds, 16, 0, 0);
}
__device__ __forceinline__ void gl_lds4(float* lds, const float* g) {
    __builtin_amdgcn_global_load_lds(
        (const __attribute__((address_space(1))) void*)g,
        (__attribute__((address_space(3))) void*)lds, 4, 0, 0);
}

__global__ __launch_bounds__(NT, 4) void multibox_kernel(
    const float* __restrict__ x, const float* __restrict__ base,
    float* __restrict__ out)
{
    __shared__ float buf[2][GROUP][LW];   // 18,432 B

    const int t  = threadIdx.x;
    const int w  = t >> 6;                // wave id: stages row w of each group
    const int l  = t & 63;                // lane
    const int c0 = blockIdx.x * COLS;
    const int i0 = blockIdx.y * SR;

    // ---- phase stagger: decorrelate co-resident blocks' DMA bursts ----
    // Cohort key differs within ANY contiguous-4 id set AND any stride-256
    // set (robust to breadth-first or depth-first block->CU mapping).
    // Each cohort step sleeps ~2560 cy ~= interval/4.
    {
        const int bid = blockIdx.y * gridDim.x + blockIdx.x;
        const int coh = (bid + (bid >> 8)) & 3;
#pragma clang loop unroll(disable)
        for (int i = 0; i < coh; ++i) __builtin_amdgcn_s_sleep(40);
    }

    const float w3  = 1.f/(7.f*9.f);
    const float w5  = 1.f/(7.f*25.f);
    const float w7  = 1.f/(7.f*49.f);
    const float w9  = 1.f/(7.f*81.f);
    const float w11 = 1.f/(7.f*121.f);
    const float w13 = 1.f/(7.f*169.f);
    const float w15 = 1.f/(7.f*225.f);

    // per-lane DMA source columns (invariant across groups).
    const int colA = min(max(c0 -   8 + 4 * l, 0), W - 4);
    const int colB =         c0 + 248 + 4 * l;             // always in-range
    const int colC = min(    c0 + 504 +     l,     W - 1); // right-edge exact

    // each wave DMAs its one row of group g into slot b: 3 instructions
    auto stage = [&](int g, int b) {
        const int rc = min(max(i0 - RAD + g * GROUP + w, 0), H - 1);
        const float* rp = x + (size_t)rc * W;
        gl_lds16(&buf[b][w][0],   rp + colA);
        gl_lds16(&buf[b][w][256], rp + colB);
        gl_lds4 (&buf[b][w][512], rp + colC);
    };

    // block x==0 only: left-edge floats 0..7 := x[row][0] (already at idx 8)
    auto patch = [&](int b) {
        if (l < 8) buf[b][w][l] = buf[b][w][8];
    };

    // Pnd[p] accumulates output row (i0 + 4g - 14 + p) before group g.
    // rr / p compile-time (inner unrolls); g stays RUNTIME (rounds 4/7 lesson).
    f32x2 Pnd[PEND];
#pragma unroll
    for (int q = 0; q < PEND; ++q) Pnd[q] = f32x2{0.f, 0.f};

    auto compute_group = [&](int b, int g) {
#pragma unroll
        for (int rr = 0; rr < GROUP; ++rr) {
            if (g * GROUP + rr < NSTAGE) {
                const float* p = &buf[b][rr][2 * t];
                f32x2 q2[9];
#pragma unroll
                for (int i = 0; i < 9; ++i) q2[i] = *(const f32x2*)(p + 2 * i);

                auto PR = [&](int a) -> f32x2 {
                    if ((a & 1) == 0) return q2[a / 2];
                    f32x2 r;
                    r.x = q2[a / 2].y;
                    r.y = q2[a / 2 + 1].x;
                    return r;
                };

                f32x2 s3  = PR(7) + PR(8) + PR(9);
                f32x2 s5  = s3  + PR(6) + PR(10);
                f32x2 s7  = s5  + PR(5) + PR(11);
                f32x2 s9  = s7  + PR(4) + PR(12);
                f32x2 s11 = s9  + PR(3) + PR(13);
                f32x2 s13 = s11 + PR(2) + PR(14);
                f32x2 s15 = s13 + PR(1) + PR(15);

                f32x2 c7 = f32x2{w15, w15} * s15;
                f32x2 c6 = c7 + f32x2{w13, w13} * s13;
                f32x2 c5 = c6 + f32x2{w11, w11} * s11;
                f32x2 c4 = c5 + f32x2{w9 , w9 } * s9;
                f32x2 c3 = c4 + f32x2{w7 , w7 } * s7;
                f32x2 c2 = c3 + f32x2{w5 , w5 } * s5;
                f32x2 c1 = c2 + f32x2{w3 , w3 } * s3;

                Pnd[rr +  0] += c7; Pnd[rr +  1] += c6; Pnd[rr +  2] += c5;
                Pnd[rr +  3] += c4; Pnd[rr +  4] += c3; Pnd[rr +  5] += c2;
                Pnd[rr +  6] += c1; Pnd[rr +  7] += c1; Pnd[rr +  8] += c1;
                Pnd[rr +  9] += c2; Pnd[rr + 10] += c3; Pnd[rr + 11] += c4;
                Pnd[rr + 12] += c5; Pnd[rr + 13] += c6; Pnd[rr + 14] += c7;
            }
        }

        // emit the completed output rows: o_ofs = 4g - 14 + p
#pragma unroll
        for (int p = 0; p < GROUP; ++p) {
            const int o_ofs = 4 * g - 14 + p;
            if (o_ofs >= 0 && o_ofs < SR) {
                const size_t bi = (size_t)(i0 + o_ofs) * W + c0 + 2 * t;
                f32x2 bm = *(const f32x2*)(base + bi);
                f32x2 ov = Pnd[p] * bm;
                __builtin_nontemporal_store(ov, (f32x2*)(out + bi));
            }
        }

        // shift window by GROUP (static indices)
#pragma unroll
        for (int p = 0; p < PEND - GROUP; ++p) Pnd[p] = Pnd[p + GROUP];
#pragma unroll
        for (int p = PEND - GROUP; p < PEND; ++p) Pnd[p] = f32x2{0.f, 0.f};
    };

    stage(0, 0);
    __syncthreads();                       // drains DMA (vmcnt) + orders LDS
    if (c0 == 0) { patch(0); __syncthreads(); }   // workgroup-uniform branch

    // MUST stay rolled (round-7 lesson: unroll hoists loads -> spill)
#pragma clang loop unroll(disable)
    for (int g = 0; g < NG - 1; ++g) {
        stage(g + 1, (g + 1) & 1);   // 3 DMA instrs/wave, issued before compute
        compute_group(g & 1, g);     // ds_read + VALU + emit (hides DMA latency)
        __syncthreads();             // next group's rows landed
        if (c0 == 0) { patch((g + 1) & 1); __syncthreads(); }
    }
    compute_group((NG - 1) & 1, NG - 1);
}

extern "C" void kernel_launch(void* const* d_in, const int* in_sizes, int n_in,
                              void* d_out, int out_size, void* d_ws, size_t ws_size,
                              hipStream_t stream) {
    const float* x    = (const float*)d_in[0];
    const float* base = (const float*)d_in[1];
    float* out        = (float*)d_out;

    dim3 grid(W / COLS, H / SR);   // (8, 128) = 1024 blocks, all co-resident
    multibox_kernel<<<grid, dim3(NT), 0, stream>>>(x, base, out);
}

// Round 20
// 44.291 us; speedup vs baseline: 4.0175x; 1.0288x over previous
//
#include <hip/hip_runtime.h>

typedef __attribute__((ext_vector_type(2))) float f32x2;

#define W 4096
#define H 4096
#define NT 256
#define NW 4
#define COLS 512                 // columns per block (2 per thread)
#define SR 32                    // output rows per block strip
#define GROUP 4                  // rows staged per barrier (1 per wave, DMA)
#define NSTAGE (SR + 14)         // 46 staged rows contribute
#define NG 12                    // 12 groups of 4
#define LW 576                   // padded staged row: 2*256 + 64 floats (DMA-linear)
#define RAD 7
#define PEND 18                  // 15 + GROUP - 1  (fits the 64-VGPR budget)

__device__ __forceinline__ void gl_lds16(float* lds, const float* g) {
    __builtin_amdgcn_global_load_lds(
        (const __attribute__((address_space(1))) void*)g,
        (__attribute__((address_space(3))) void*)lds, 16, 0, 0);
}
__device__ __forceinline__ void gl_lds4(float* lds, const float* g) {
    __builtin_amdgcn_global_load_lds(
        (const __attribute__((address_space(1))) void*)g,
        (__attribute__((address_space(3))) void*)lds, 4, 0, 0);
}

__global__ __launch_bounds__(NT, 4) void multibox_kernel(
    const float* __restrict__ x, const float* __restrict__ base,
    float* __restrict__ out)
{
    __shared__ float buf[2][GROUP][LW];   // 18,432 B

    const int t  = threadIdx.x;
    const int w  = t >> 6;                // wave id: stages row w of each group
    const int l  = t & 63;                // lane
    const int c0 = blockIdx.x * COLS;
    const int i0 = blockIdx.y * SR;

    // Boustrophedon: odd strips sweep bottom-up so vertically-adjacent strips
    // touch their shared 14 halo rows close in TIME (~6us apart instead of
    // ~25us) -> halo re-reads hit L2 instead of HBM. The scatter weights are
    // symmetric in the row offset, so only the physical<->logical row mapping
    // changes; the entire logical pipeline (Pnd, cum, emit window) is as-is.
    const bool flip = blockIdx.y & 1;

    const float w3  = 1.f/(7.f*9.f);
    const float w5  = 1.f/(7.f*25.f);
    const float w7  = 1.f/(7.f*49.f);
    const float w9  = 1.f/(7.f*81.f);
    const float w11 = 1.f/(7.f*121.f);
    const float w13 = 1.f/(7.f*169.f);
    const float w15 = 1.f/(7.f*225.f);

    // per-lane DMA source columns (invariant across groups).
    const int colA = min(max(c0 -   8 + 4 * l, 0), W - 4);
    const int colB =         c0 + 248 + 4 * l;             // always in-range
    const int colC = min(    c0 + 504 +     l,     W - 1); // right-edge exact

    // each wave DMAs its one row (logical idx -> physical srow) of group g
    auto stage = [&](int g, int b) {
        const int idx  = g * GROUP + w;                       // logical step
        const int srow = flip ? (NSTAGE - 1 - idx) : idx;     // physical offset
        const int rc   = min(max(i0 - RAD + srow, 0), H - 1);
        const float* rp = x + (size_t)rc * W;
        gl_lds16(&buf[b][w][0],   rp + colA);
        gl_lds16(&buf[b][w][256], rp + colB);
        gl_lds4 (&buf[b][w][512], rp + colC);
    };

    // block x==0 only: left-edge floats 0..7 := x[row][0] (already at idx 8)
    auto patch = [&](int b) {
        if (l < 8) buf[b][w][l] = buf[b][w][8];
    };

    // Pnd[p] accumulates LOGICAL output row (4g - 14 + p) before group g.
    f32x2 Pnd[PEND];
#pragma unroll
    for (int q = 0; q < PEND; ++q) Pnd[q] = f32x2{0.f, 0.f};

    auto compute_group = [&](int b, int g) {
#pragma unroll
        for (int rr = 0; rr < GROUP; ++rr) {
            if (g * GROUP + rr < NSTAGE) {
                const float* p = &buf[b][rr][2 * t];
                f32x2 q2[9];
#pragma unroll
                for (int i = 0; i < 9; ++i) q2[i] = *(const f32x2*)(p + 2 * i);

                auto PR = [&](int a) -> f32x2 {
                    if ((a & 1) == 0) return q2[a / 2];
                    f32x2 r;
                    r.x = q2[a / 2].y;
                    r.y = q2[a / 2 + 1].x;
                    return r;
                };

                f32x2 s3  = PR(7) + PR(8) + PR(9);
                f32x2 s5  = s3  + PR(6) + PR(10);
                f32x2 s7  = s5  + PR(5) + PR(11);
                f32x2 s9  = s7  + PR(4) + PR(12);
                f32x2 s11 = s9  + PR(3) + PR(13);
                f32x2 s13 = s11 + PR(2) + PR(14);
                f32x2 s15 = s13 + PR(1) + PR(15);

                f32x2 c7 = f32x2{w15, w15} * s15;
                f32x2 c6 = c7 + f32x2{w13, w13} * s13;
                f32x2 c5 = c6 + f32x2{w11, w11} * s11;
                f32x2 c4 = c5 + f32x2{w9 , w9 } * s9;
                f32x2 c3 = c4 + f32x2{w7 , w7 } * s7;
                f32x2 c2 = c3 + f32x2{w5 , w5 } * s5;
                f32x2 c1 = c2 + f32x2{w3 , w3 } * s3;

                Pnd[rr +  0] += c7; Pnd[rr +  1] += c6; Pnd[rr +  2] += c5;
                Pnd[rr +  3] += c4; Pnd[rr +  4] += c3; Pnd[rr +  5] += c2;
                Pnd[rr +  6] += c1; Pnd[rr +  7] += c1; Pnd[rr +  8] += c1;
                Pnd[rr +  9] += c2; Pnd[rr + 10] += c3; Pnd[rr + 11] += c4;
                Pnd[rr + 12] += c5; Pnd[rr + 13] += c6; Pnd[rr + 14] += c7;
            }
        }

        // emit completed logical rows ol = 4g - 14 + p -> physical row
#pragma unroll
        for (int p = 0; p < GROUP; ++p) {
            const int ol = 4 * g - 14 + p;
            if (ol >= 0 && ol < SR) {
                const int orow = flip ? (i0 + SR - 1 - ol) : (i0 + ol);
                const size_t bi = (size_t)orow * W + c0 + 2 * t;
                f32x2 bm = *(const f32x2*)(base + bi);
                f32x2 ov = Pnd[p] * bm;
                __builtin_nontemporal_store(ov, (f32x2*)(out + bi));
            }
        }

        // shift window by GROUP (static indices)
#pragma unroll
        for (int p = 0; p < PEND - GROUP; ++p) Pnd[p] = Pnd[p + GROUP];
#pragma unroll
        for (int p = PEND - GROUP; p < PEND; ++p) Pnd[p] = f32x2{0.f, 0.f};
    };

    stage(0, 0);
    __syncthreads();                       // drains DMA (vmcnt) + orders LDS
    if (c0 == 0) { patch(0); __syncthreads(); }   // workgroup-uniform branch

    // MUST stay rolled (round-7 lesson: unroll hoists loads -> spill)
#pragma clang loop unroll(disable)
    for (int g = 0; g < NG - 1; ++g) {
        stage(g + 1, (g + 1) & 1);   // 3 DMA instrs/wave, issued before compute
        compute_group(g & 1, g);     // ds_read + VALU + emit (hides DMA latency)
        __syncthreads();             // next group's rows landed
        if (c0 == 0) { patch((g + 1) & 1); __syncthreads(); }
    }
    compute_group((NG - 1) & 1, NG - 1);
}

extern "C" void kernel_launch(void* const* d_in, const int* in_sizes, int n_in,
                              void* d_out, int out_size, void* d_ws, size_t ws_size,
                              hipStream_t stream) {
    const float* x    = (const float*)d_in[0];
    const float* base = (const float*)d_in[1];
    float* out        = (float*)d_out;

    dim3 grid(W / COLS, H / SR);   // (8, 128) = 1024 blocks, all co-resident
    multibox_kernel<<<grid, dim3(NT), 0, stream>>>(x, base, out);
}